// Round 4
// baseline (308.466 us; speedup 1.0000x reference)
//
#include <hip/hip_runtime.h>
#include <hip/hip_bf16.h>

#define HW 16384
#define CC 192
#define BB 8
#define NHD 4
#define HD 48

typedef __attribute__((ext_vector_type(8))) short  short8;
typedef __attribute__((ext_vector_type(4))) float  f32x4;

static __device__ __forceinline__ unsigned short f2bf(float f) {
  unsigned u = __float_as_uint(f);
  u += 0x7fffu + ((u >> 16) & 1u);          // round-to-nearest-even
  return (unsigned short)(u >> 16);
}
// two fp32 -> packed bf16x2 (compiler emits v_cvt_pk_bf16_f32)
static __device__ __forceinline__ unsigned pk2bf(float lo, float hi) {
  __hip_bfloat162 h = __float22bfloat162_rn(make_float2(lo, hi));
  return *reinterpret_cast<unsigned*>(&h);
}

// Cast Wq (192x192) and Wk (= Wkv rows 0..191) fp32 -> bf16, contiguous.
__global__ __launch_bounds__(256) void cast_w_kernel(
    const float* __restrict__ Wq, const float* __restrict__ Wkv,
    unsigned short* __restrict__ Wb)
{
  const int i = blockIdx.x * 256 + threadIdx.x;   // 0 .. 2*CC*CC-1
  const float v = (i < CC*CC) ? Wq[i] : Wkv[i - CC*CC];
  Wb[i] = f2bf(v);
}

// Pipelined channel-projection GEMM. 256 threads (wave = head), 256 pos/block
// in 4 tiles of 64, reg-staged prefetch (loads for t+1 in flight during
// compute of t; vmcnt drain sits after the MFMA+epilogue).
// MODE 0: q/k proj (blockIdx.z: 0=q from x_q, 1=k from x_k), +bias, l2norm, bf16 out
// MODE 1: final    (x_k in, per-batch W3b bf16 + b3 fp32 bias, fp32 out)
template<int MODE>
__global__ __launch_bounds__(256) void proj_pipe(
    const float* __restrict__ x_q, const float* __restrict__ x_k,
    const unsigned short* __restrict__ wsrc,
    const float* __restrict__ bias0, const float* __restrict__ bias1,
    unsigned short* __restrict__ oq, unsigned short* __restrict__ ok,
    float* __restrict__ of)
{
  const int tid  = threadIdx.x;
  const int lane = tid & 63;
  const int wv   = tid >> 6;          // wave = head (48 rows)
  const int b    = blockIdx.y;
  const int z    = blockIdx.z;
  const int p0   = blockIdx.x * 256;
  const int l15  = lane & 15;
  const int lg   = lane >> 4;
  const int qd   = tid & 15;          // position-quad owned for staging

  __shared__ unsigned short Xt[64][200];  // 64 pos x (192+8) bf16

  const float* X = (MODE == 0 ? (z ? x_k : x_q) : x_k) + (size_t)b*CC*HW;
  const unsigned short* Wb = (MODE == 0) ? wsrc + (size_t)z*CC*CC
                                         : wsrc + (size_t)b*CC*CC;
  const float* bias = (MODE == 0) ? (z ? bias1 : bias0) : bias0 + (size_t)b*CC;

  short8 afr[6][3];
  #pragma unroll
  for (int kk = 0; kk < 6; ++kk)
    #pragma unroll
    for (int mt = 0; mt < 3; ++mt)
      afr[kk][mt] = *(const short8*)(Wb + (size_t)(wv*48 + mt*16 + l15)*CC + kk*32 + lg*8);

  float bv[3][4];
  #pragma unroll
  for (int mt = 0; mt < 3; ++mt)
    #pragma unroll
    for (int r = 0; r < 4; ++r)
      bv[mt][r] = bias[wv*48 + mt*16 + lg*4 + r];

  f32x4 pre[12];                      // in-flight tile (12 dwordx4)

  auto LOADT = [&](int pb) {
    #pragma unroll
    for (int i = 0; i < 6; ++i) {
      const int cp = (tid >> 4) + i*16;
      const float* base = X + (size_t)(2*cp)*HW + pb + qd*4;
      pre[2*i]   = *(const f32x4*)(base);
      pre[2*i+1] = *(const f32x4*)(base + HW);
    }
  };
  auto WRITET = [&]() {
    #pragma unroll
    for (int i = 0; i < 6; ++i) {
      const int cp = (tid >> 4) + i*16;
      #pragma unroll
      for (int j = 0; j < 4; ++j)
        *(unsigned*)&Xt[qd*4 + j][2*cp] = pk2bf(pre[2*i][j], pre[2*i+1][j]);
    }
  };

  unsigned short* Obf = nullptr;
  float* Ofp = nullptr;
  if (MODE == 0) Obf = (z ? ok : oq) + (size_t)b*CC*HW;
  else           Ofp = of + (size_t)b*CC*HW;

  auto COMPUTE = [&](int pb) {
    f32x4 acc[3][4];
    #pragma unroll
    for (int mt = 0; mt < 3; ++mt)
      #pragma unroll
      for (int nt = 0; nt < 4; ++nt)
        acc[mt][nt] = (f32x4){0.f, 0.f, 0.f, 0.f};

    #pragma unroll
    for (int kk = 0; kk < 6; ++kk) {
      short8 bfr[4];
      #pragma unroll
      for (int nt = 0; nt < 4; ++nt)
        bfr[nt] = *(const short8*)&Xt[nt*16 + l15][kk*32 + lg*8];
      #pragma unroll
      for (int mt = 0; mt < 3; ++mt)
        #pragma unroll
        for (int nt = 0; nt < 4; ++nt)
          acc[mt][nt] = __builtin_amdgcn_mfma_f32_16x16x32_bf16(
              afr[kk][mt], bfr[nt], acc[mt][nt], 0, 0, 0);
    }

    #pragma unroll
    for (int nt = 0; nt < 4; ++nt) {
      float v[3][4];
      float ss = 0.f;
      #pragma unroll
      for (int mt = 0; mt < 3; ++mt)
        #pragma unroll
        for (int r = 0; r < 4; ++r) {
          const float x = acc[mt][nt][r] + bv[mt][r];
          v[mt][r] = x;
          ss += x*x;
        }
      if (MODE == 0) {                 // l2norm over the head's 48 rows
        ss += __shfl_xor(ss, 16);
        ss += __shfl_xor(ss, 32);
        const float rn = 1.0f / fmaxf(sqrtf(ss), 1e-12f);
        #pragma unroll
        for (int mt = 0; mt < 3; ++mt)
          #pragma unroll
          for (int r = 0; r < 4; ++r)
            v[mt][r] *= rn;
      }
      const int col = pb + nt*16 + l15;
      if (MODE == 0) {
        #pragma unroll
        for (int mt = 0; mt < 3; ++mt)
          #pragma unroll
          for (int r = 0; r < 4; ++r)
            Obf[(size_t)(wv*48 + mt*16 + lg*4 + r)*HW + col] = f2bf(v[mt][r]);
      } else {
        #pragma unroll
        for (int mt = 0; mt < 3; ++mt)
          #pragma unroll
          for (int r = 0; r < 4; ++r)
            Ofp[(size_t)(wv*48 + mt*16 + lg*4 + r)*HW + col] = v[mt][r];
      }
    }
  };

  // --- pipeline: loads of t+1 in flight while computing t ---
  LOADT(p0);
  WRITET();
  __syncthreads();
  for (int t = 0; t < 4; ++t) {
    if (t < 3) LOADT(p0 + (t+1)*64);
    COMPUTE(p0 + t*64);
    __syncthreads();                   // all waves done reading Xt
    if (t < 3) { WRITET(); __syncthreads(); }
  }
}

// Gram: G[b,h,c,k] = sum_p qn[c,p]*kn[k,p]; K-split 32-way, partials to ws.
__global__ __launch_bounds__(256) void gram_kernel(
    const unsigned short* __restrict__ Qn,
    const unsigned short* __restrict__ Kn,
    float* __restrict__ Gpart)
{
  const int tid  = threadIdx.x;
  const int lane = tid & 63;
  const int wv   = tid >> 6;
  const int ks   = blockIdx.x;   // 0..7
  const int h    = blockIdx.y;   // 0..3
  const int b    = blockIdx.z;   // 0..7
  const int l15  = lane & 15;
  const int lg   = lane >> 4;

  const unsigned short* Qb = Qn + ((size_t)b*CC + h*HD)*HW;
  const unsigned short* Kb = Kn + ((size_t)b*CC + h*HD)*HW;
  const int pbase = ks*2048 + wv*512;

  f32x4 acc[3][3];
  #pragma unroll
  for (int mt = 0; mt < 3; ++mt)
    #pragma unroll
    for (int nt = 0; nt < 3; ++nt)
      acc[mt][nt] = (f32x4){0.f, 0.f, 0.f, 0.f};

  for (int it = 0; it < 16; ++it) {
    const int p = pbase + it*32 + lg*8;
    short8 a[3], bb[3];
    #pragma unroll
    for (int mt = 0; mt < 3; ++mt)
      a[mt] = *(const short8*)(Qb + (size_t)(mt*16 + l15)*HW + p);
    #pragma unroll
    for (int nt = 0; nt < 3; ++nt)
      bb[nt] = *(const short8*)(Kb + (size_t)(nt*16 + l15)*HW + p);
    #pragma unroll
    for (int mt = 0; mt < 3; ++mt)
      #pragma unroll
      for (int nt = 0; nt < 3; ++nt)
        acc[mt][nt] = __builtin_amdgcn_mfma_f32_16x16x32_bf16(
            a[mt], bb[nt], acc[mt][nt], 0, 0, 0);
  }

  const int slot = ks*4 + wv;     // 0..31
  float* G = Gpart + ((size_t)(b*NHD + h)*32 + slot)*2304;
  #pragma unroll
  for (int mt = 0; mt < 3; ++mt)
    #pragma unroll
    for (int nt = 0; nt < 3; ++nt)
      #pragma unroll
      for (int r = 0; r < 4; ++r)
        G[(mt*16 + lg*4 + r)*HD + nt*16 + l15] = acc[mt][nt][r];
}

// Per (b,h): reduce Gram partials, wave-parallel row softmax, then
// M[b][o][h*48+k] = sum_c Wp[o][h*48+c] * attn[c][k]  (fp32 out).
__global__ __launch_bounds__(256) void attn_m_kernel(
    const float* __restrict__ Gpart,
    const float* __restrict__ Wp,
    const float* __restrict__ temp,
    float* __restrict__ Mf)
{
  __shared__ float att[HD][52];        // +4 pad
  const int bh  = blockIdx.x;          // 0..31
  const int b   = bh >> 2, h = bh & 3;
  const int tid = threadIdx.x;
  const float* src = Gpart + (size_t)bh*32*2304;

  #pragma unroll
  for (int i = 0; i < 9; ++i) {
    const int e = tid + i*256;         // 2304 = 9*256
    float s = 0.f;
    #pragma unroll
    for (int k = 0; k < 32; ++k) s += src[(size_t)k*2304 + e];
    att[e/48][e%48] = s;
  }
  __syncthreads();

  const int g = tid >> 2, sl = tid & 3;
  if (g < HD) {
    const float t = temp[h];
    const float scale = 0.1f / (1.0f + expf(-t));   // 0.1*sigmoid(t)
    float* row = att[g];
    float m = -1e30f;
    #pragma unroll
    for (int jj = 0; jj < 12; ++jj) m = fmaxf(m, row[sl + jj*4]);
    m = fmaxf(m, __shfl_xor(m, 1));
    m = fmaxf(m, __shfl_xor(m, 2));
    float ev[12];
    float s = 0.f;
    #pragma unroll
    for (int jj = 0; jj < 12; ++jj) {
      const float e = expf((row[sl + jj*4] - m) * scale);
      ev[jj] = e; s += e;
    }
    s += __shfl_xor(s, 1);
    s += __shfl_xor(s, 2);
    const float inv = 1.0f / s;
    #pragma unroll
    for (int jj = 0; jj < 12; ++jj) row[sl + jj*4] = ev[jj] * inv;
  }
  __syncthreads();

  #pragma unroll
  for (int i = 0; i < 36; ++i) {
    const int idx = tid + i*256;       // 0..9215
    const int o = idx / HD, k2 = idx % HD;
    const float* wrow = Wp + (size_t)o*CC + h*HD;
    float s = 0.f;
    #pragma unroll
    for (int c = 0; c < HD; ++c) s += wrow[c] * att[c][k2];
    Mf[(size_t)b*CC*CC + (size_t)o*CC + h*HD + k2] = s;
  }
}

// W3_b = M_b @ Wv (bf16 out), b3_b = M_b @ bv + bp (fp32).
// grid (BB, 6): block owns 32 o-rows; thread (o=oc*32+tid/8, j-chunk=24).
__global__ __launch_bounds__(256) void w3_kernel(
    const float* __restrict__ Mf, const float* __restrict__ Wkv,
    const float* __restrict__ bkv, const float* __restrict__ bp,
    unsigned short* __restrict__ W3b, float* __restrict__ b3)
{
  const int b  = blockIdx.x, oc = blockIdx.y;
  const int tid = threadIdx.x;
  const int o  = oc*32 + (tid >> 3);
  const int j0 = (tid & 7) * 24;
  const float* Mrow = Mf + ((size_t)b*CC + o)*CC;
  const float* Wv = Wkv + (size_t)CC*CC;       // rows 192..383 of Wkv

  float acc[24];
  #pragma unroll
  for (int j = 0; j < 24; ++j) acc[j] = 0.f;
  for (int k = 0; k < CC; ++k) {
    const float m = Mrow[k];
    const float* wr = Wv + (size_t)k*CC + j0;
    #pragma unroll
    for (int j = 0; j < 24; ++j) acc[j] += m * wr[j];
  }
  unsigned short* dst = W3b + ((size_t)b*CC + o)*CC + j0;
  #pragma unroll
  for (int j = 0; j < 24; ++j) dst[j] = f2bf(acc[j]);

  if ((tid & 7) == 0) {
    const float* bvv = bkv + CC;
    float s = 0.f;
    for (int k = 0; k < CC; ++k) s += Mrow[k] * bvv[k];
    b3[(size_t)b*CC + o] = s + bp[o];
  }
}

extern "C" void kernel_launch(void* const* d_in, const int* in_sizes, int n_in,
                              void* d_out, int out_size, void* d_ws, size_t ws_size,
                              hipStream_t stream)
{
  (void)in_sizes; (void)n_in; (void)out_size; (void)ws_size;
  const float* x_q  = (const float*)d_in[0];
  const float* x_k  = (const float*)d_in[1];
  const float* Wq   = (const float*)d_in[2];
  const float* bq   = (const float*)d_in[3];
  const float* Wkv  = (const float*)d_in[4];
  const float* bkv  = (const float*)d_in[5];
  const float* Wp   = (const float*)d_in[6];
  const float* bp   = (const float*)d_in[7];
  const float* temp = (const float*)d_in[8];

  const size_t SQ = (size_t)BB*CC*HW;
  char* p = (char*)d_ws;
  unsigned short* qn = (unsigned short*)p;  p += SQ*sizeof(unsigned short);
  unsigned short* kn = (unsigned short*)p;  p += SQ*sizeof(unsigned short);
  float* gpart = (float*)p;                 p += (size_t)BB*NHD*32*2304*sizeof(float);
  float* mf = (float*)p;                    p += (size_t)BB*CC*CC*sizeof(float);
  unsigned short* w3b = (unsigned short*)p; p += (size_t)BB*CC*CC*sizeof(unsigned short);
  float* b3 = (float*)p;                    p += (size_t)BB*CC*sizeof(float);
  unsigned short* wb = (unsigned short*)p;  // 2*CC*CC bf16 (Wq | Wk)

  cast_w_kernel<<<dim3((2*CC*CC)/256), 256, 0, stream>>>(Wq, Wkv, wb);

  // fused q+k projection (z: 0=q, 1=k)
  proj_pipe<0><<<dim3(HW/256, BB, 2), 256, 0, stream>>>(
      x_q, x_k, wb, bq, bkv, qn, kn, nullptr);

  gram_kernel<<<dim3(8, NHD, BB), 256, 0, stream>>>(qn, kn, gpart);
  attn_m_kernel<<<dim3(BB*NHD), 256, 0, stream>>>(gpart, Wp, temp, mf);
  w3_kernel<<<dim3(BB, 6), 256, 0, stream>>>(mf, Wkv, bkv, bp, w3b, b3);

  // final: out = W3_b @ x_k + b3_b
  proj_pipe<1><<<dim3(HW/256, BB, 1), 256, 0, stream>>>(
      x_q, x_k, w3b, b3, nullptr, nullptr, nullptr, (float*)d_out);
}

// Round 5
// 222.038 us; speedup vs baseline: 1.3892x; 1.3892x over previous
//
#include <hip/hip_runtime.h>
#include <hip/hip_bf16.h>

#define HW 16384
#define CC 192
#define BB 8
#define NHD 4
#define HD 48

typedef __attribute__((ext_vector_type(8))) short  short8;
typedef __attribute__((ext_vector_type(4))) float  f32x4;

static __device__ __forceinline__ unsigned short f2bf(float f) {
  unsigned u = __float_as_uint(f);
  u += 0x7fffu + ((u >> 16) & 1u);          // round-to-nearest-even
  return (unsigned short)(u >> 16);
}
// two fp32 -> packed bf16x2 (compiler emits v_cvt_pk_bf16_f32)
static __device__ __forceinline__ unsigned pk2bf(float lo, float hi) {
  __hip_bfloat162 h = __float22bfloat162_rn(make_float2(lo, hi));
  return *reinterpret_cast<unsigned*>(&h);
}

// Cast Wq (192x192) and Wk (= Wkv rows 0..191) fp32 -> bf16, contiguous.
__global__ __launch_bounds__(256) void cast_w_kernel(
    const float* __restrict__ Wq, const float* __restrict__ Wkv,
    unsigned short* __restrict__ Wb)
{
  const int i = blockIdx.x * 256 + threadIdx.x;   // 0 .. 2*CC*CC-1
  const float v = (i < CC*CC) ? Wq[i] : Wkv[i - CC*CC];
  Wb[i] = f2bf(v);
}

// Pipelined channel-projection GEMM. 256 threads (wave = head), 256 pos/block
// in 4 tiles of 64, reg-staged prefetch (loads for t+1 in flight during
// compute of t; vmcnt drain sits after the MFMA+epilogue).
// MODE 0: q/k proj (blockIdx.z: 0=q from x_q, 1=k from x_k), +bias, l2norm, bf16 out
// MODE 1: final    (x_k in, per-batch W3b bf16 + b3 fp32 bias, fp32 out)
template<int MODE>
__global__ __launch_bounds__(256) void proj_pipe(
    const float* __restrict__ x_q, const float* __restrict__ x_k,
    const unsigned short* __restrict__ wsrc,
    const float* __restrict__ bias0, const float* __restrict__ bias1,
    unsigned short* __restrict__ oq, unsigned short* __restrict__ ok,
    float* __restrict__ of)
{
  const int tid  = threadIdx.x;
  const int lane = tid & 63;
  const int wv   = tid >> 6;          // wave = head (48 rows)
  const int b    = blockIdx.y;
  const int z    = blockIdx.z;
  const int p0   = blockIdx.x * 256;
  const int l15  = lane & 15;
  const int lg   = lane >> 4;
  const int qd   = tid & 15;          // position-quad owned for staging

  __shared__ unsigned short Xt[64][200];  // 64 pos x (192+8) bf16

  const float* X = (MODE == 0 ? (z ? x_k : x_q) : x_k) + (size_t)b*CC*HW;
  const unsigned short* Wb = (MODE == 0) ? wsrc + (size_t)z*CC*CC
                                         : wsrc + (size_t)b*CC*CC;
  const float* bias = (MODE == 0) ? (z ? bias1 : bias0) : bias0 + (size_t)b*CC;

  short8 afr[6][3];
  #pragma unroll
  for (int kk = 0; kk < 6; ++kk)
    #pragma unroll
    for (int mt = 0; mt < 3; ++mt)
      afr[kk][mt] = *(const short8*)(Wb + (size_t)(wv*48 + mt*16 + l15)*CC + kk*32 + lg*8);

  float bv[3][4];
  #pragma unroll
  for (int mt = 0; mt < 3; ++mt)
    #pragma unroll
    for (int r = 0; r < 4; ++r)
      bv[mt][r] = bias[wv*48 + mt*16 + lg*4 + r];

  f32x4 pre[12];                      // in-flight tile (12 dwordx4)

  auto LOADT = [&](int pb) {
    #pragma unroll
    for (int i = 0; i < 6; ++i) {
      const int cp = (tid >> 4) + i*16;
      const float* base = X + (size_t)(2*cp)*HW + pb + qd*4;
      pre[2*i]   = *(const f32x4*)(base);
      pre[2*i+1] = *(const f32x4*)(base + HW);
    }
  };
  auto WRITET = [&]() {
    #pragma unroll
    for (int i = 0; i < 6; ++i) {
      const int cp = (tid >> 4) + i*16;
      #pragma unroll
      for (int j = 0; j < 4; ++j)
        *(unsigned*)&Xt[qd*4 + j][2*cp] = pk2bf(pre[2*i][j], pre[2*i+1][j]);
    }
  };

  unsigned short* Obf = nullptr;
  float* Ofp = nullptr;
  if (MODE == 0) Obf = (z ? ok : oq) + (size_t)b*CC*HW;
  else           Ofp = of + (size_t)b*CC*HW;

  auto COMPUTE = [&](int pb) {
    f32x4 acc[3][4];
    #pragma unroll
    for (int mt = 0; mt < 3; ++mt)
      #pragma unroll
      for (int nt = 0; nt < 4; ++nt)
        acc[mt][nt] = (f32x4){0.f, 0.f, 0.f, 0.f};

    #pragma unroll
    for (int kk = 0; kk < 6; ++kk) {
      short8 bfr[4];
      #pragma unroll
      for (int nt = 0; nt < 4; ++nt)
        bfr[nt] = *(const short8*)&Xt[nt*16 + l15][kk*32 + lg*8];
      #pragma unroll
      for (int mt = 0; mt < 3; ++mt)
        #pragma unroll
        for (int nt = 0; nt < 4; ++nt)
          acc[mt][nt] = __builtin_amdgcn_mfma_f32_16x16x32_bf16(
              afr[kk][mt], bfr[nt], acc[mt][nt], 0, 0, 0);
    }

    #pragma unroll
    for (int nt = 0; nt < 4; ++nt) {
      float v[3][4];
      float ss = 0.f;
      #pragma unroll
      for (int mt = 0; mt < 3; ++mt)
        #pragma unroll
        for (int r = 0; r < 4; ++r) {
          const float x = acc[mt][nt][r] + bv[mt][r];
          v[mt][r] = x;
          ss += x*x;
        }
      if (MODE == 0) {                 // l2norm over the head's 48 rows
        ss += __shfl_xor(ss, 16);
        ss += __shfl_xor(ss, 32);
        const float rn = 1.0f / fmaxf(sqrtf(ss), 1e-12f);
        #pragma unroll
        for (int mt = 0; mt < 3; ++mt)
          #pragma unroll
          for (int r = 0; r < 4; ++r)
            v[mt][r] *= rn;
      }
      const int col = pb + nt*16 + l15;
      if (MODE == 0) {
        #pragma unroll
        for (int mt = 0; mt < 3; ++mt)
          #pragma unroll
          for (int r = 0; r < 4; ++r)
            Obf[(size_t)(wv*48 + mt*16 + lg*4 + r)*HW + col] = f2bf(v[mt][r]);
      } else {
        #pragma unroll
        for (int mt = 0; mt < 3; ++mt)
          #pragma unroll
          for (int r = 0; r < 4; ++r)
            Ofp[(size_t)(wv*48 + mt*16 + lg*4 + r)*HW + col] = v[mt][r];
      }
    }
  };

  // --- pipeline: loads of t+1 in flight while computing t ---
  LOADT(p0);
  WRITET();
  __syncthreads();
  for (int t = 0; t < 4; ++t) {
    if (t < 3) LOADT(p0 + (t+1)*64);
    COMPUTE(p0 + t*64);
    __syncthreads();                   // all waves done reading Xt
    if (t < 3) { WRITET(); __syncthreads(); }
  }
}

// Gram: G[b,h,c,k] = sum_p qn[c,p]*kn[k,p]; K-split 32-way, partials to ws.
__global__ __launch_bounds__(256) void gram_kernel(
    const unsigned short* __restrict__ Qn,
    const unsigned short* __restrict__ Kn,
    float* __restrict__ Gpart)
{
  const int tid  = threadIdx.x;
  const int lane = tid & 63;
  const int wv   = tid >> 6;
  const int ks   = blockIdx.x;   // 0..7
  const int h    = blockIdx.y;   // 0..3
  const int b    = blockIdx.z;   // 0..7
  const int l15  = lane & 15;
  const int lg   = lane >> 4;

  const unsigned short* Qb = Qn + ((size_t)b*CC + h*HD)*HW;
  const unsigned short* Kb = Kn + ((size_t)b*CC + h*HD)*HW;
  const int pbase = ks*2048 + wv*512;

  f32x4 acc[3][3];
  #pragma unroll
  for (int mt = 0; mt < 3; ++mt)
    #pragma unroll
    for (int nt = 0; nt < 3; ++nt)
      acc[mt][nt] = (f32x4){0.f, 0.f, 0.f, 0.f};

  for (int it = 0; it < 16; ++it) {
    const int p = pbase + it*32 + lg*8;
    short8 a[3], bb[3];
    #pragma unroll
    for (int mt = 0; mt < 3; ++mt)
      a[mt] = *(const short8*)(Qb + (size_t)(mt*16 + l15)*HW + p);
    #pragma unroll
    for (int nt = 0; nt < 3; ++nt)
      bb[nt] = *(const short8*)(Kb + (size_t)(nt*16 + l15)*HW + p);
    #pragma unroll
    for (int mt = 0; mt < 3; ++mt)
      #pragma unroll
      for (int nt = 0; nt < 3; ++nt)
        acc[mt][nt] = __builtin_amdgcn_mfma_f32_16x16x32_bf16(
            a[mt], bb[nt], acc[mt][nt], 0, 0, 0);
  }

  const int slot = ks*4 + wv;     // 0..31
  float* G = Gpart + ((size_t)(b*NHD + h)*32 + slot)*2304;
  #pragma unroll
  for (int mt = 0; mt < 3; ++mt)
    #pragma unroll
    for (int nt = 0; nt < 3; ++nt)
      #pragma unroll
      for (int r = 0; r < 4; ++r)
        G[(mt*16 + lg*4 + r)*HD + nt*16 + l15] = acc[mt][nt][r];
}

// Per (b,h): reduce Gram partials, wave-parallel row softmax, then
// M[b][o][h*48+k] = sum_c Wp[o][h*48+c] * attn[c][k]  (fp32 out).
__global__ __launch_bounds__(256) void attn_m_kernel(
    const float* __restrict__ Gpart,
    const float* __restrict__ Wp,
    const float* __restrict__ temp,
    float* __restrict__ Mf)
{
  __shared__ float att[HD][52];        // +4 pad
  const int bh  = blockIdx.x;          // 0..31
  const int b   = bh >> 2, h = bh & 3;
  const int tid = threadIdx.x;
  const float* src = Gpart + (size_t)bh*32*2304;

  #pragma unroll
  for (int i = 0; i < 9; ++i) {
    const int e = tid + i*256;         // 2304 = 9*256
    float s = 0.f;
    #pragma unroll
    for (int k = 0; k < 32; ++k) s += src[(size_t)k*2304 + e];
    att[e/48][e%48] = s;
  }
  __syncthreads();

  const int g = tid >> 2, sl = tid & 3;
  if (g < HD) {
    const float t = temp[h];
    const float scale = 0.1f / (1.0f + expf(-t));   // 0.1*sigmoid(t)
    float* row = att[g];
    float m = -1e30f;
    #pragma unroll
    for (int jj = 0; jj < 12; ++jj) m = fmaxf(m, row[sl + jj*4]);
    m = fmaxf(m, __shfl_xor(m, 1));
    m = fmaxf(m, __shfl_xor(m, 2));
    float ev[12];
    float s = 0.f;
    #pragma unroll
    for (int jj = 0; jj < 12; ++jj) {
      const float e = expf((row[sl + jj*4] - m) * scale);
      ev[jj] = e; s += e;
    }
    s += __shfl_xor(s, 1);
    s += __shfl_xor(s, 2);
    const float inv = 1.0f / s;
    #pragma unroll
    for (int jj = 0; jj < 12; ++jj) row[sl + jj*4] = ev[jj] * inv;
  }
  __syncthreads();

  #pragma unroll
  for (int i = 0; i < 36; ++i) {
    const int idx = tid + i*256;       // 0..9215
    const int o = idx / HD, k2 = idx % HD;
    const float* wrow = Wp + (size_t)o*CC + h*HD;
    float s = 0.f;
    #pragma unroll
    for (int c = 0; c < HD; ++c) s += wrow[c] * att[c][k2];
    Mf[(size_t)b*CC*CC + (size_t)o*CC + h*HD + k2] = s;
  }
}

// W3_b = M_b @ Wv (bf16 out), b3_b = M_b @ bv + bp (fp32).
// grid (BB, 24), 192 threads: thread = column j (coalesced Wv reads),
// block = 8 o-rows (M/bv values are lane-uniform -> scalar loads), 8-way ILP.
__global__ __launch_bounds__(192) void w3_kernel(
    const float* __restrict__ Mf, const float* __restrict__ Wkv,
    const float* __restrict__ bkv, const float* __restrict__ bp,
    unsigned short* __restrict__ W3b, float* __restrict__ b3)
{
  const int b  = blockIdx.x;
  const int o0 = blockIdx.y * 8;
  const int j  = threadIdx.x;
  const float* M  = Mf + ((size_t)b*CC + o0)*CC;   // 8 rows x 192, uniform
  const float* Wv = Wkv + (size_t)CC*CC;           // rows 192..383 of Wkv
  const float* bv = bkv + CC;

  float acc[8]  = {0.f,0.f,0.f,0.f,0.f,0.f,0.f,0.f};
  float bacc[8] = {0.f,0.f,0.f,0.f,0.f,0.f,0.f,0.f};
  #pragma unroll 4
  for (int k = 0; k < CC; ++k) {
    const float w  = Wv[(size_t)k*CC + j];   // coalesced across lanes
    const float bk = bv[k];                  // uniform
    #pragma unroll
    for (int r = 0; r < 8; ++r) {
      const float m = M[r*CC + k];           // uniform -> s_load
      acc[r]  += m * w;
      bacc[r] += m * bk;
    }
  }
  unsigned short* dst = W3b + ((size_t)b*CC + o0)*CC + j;
  #pragma unroll
  for (int r = 0; r < 8; ++r) dst[(size_t)r*CC] = f2bf(acc[r]);
  if (j < 8) b3[(size_t)b*CC + o0 + j] = bacc[j] + bp[o0 + j];
}

extern "C" void kernel_launch(void* const* d_in, const int* in_sizes, int n_in,
                              void* d_out, int out_size, void* d_ws, size_t ws_size,
                              hipStream_t stream)
{
  (void)in_sizes; (void)n_in; (void)out_size; (void)ws_size;
  const float* x_q  = (const float*)d_in[0];
  const float* x_k  = (const float*)d_in[1];
  const float* Wq   = (const float*)d_in[2];
  const float* bq   = (const float*)d_in[3];
  const float* Wkv  = (const float*)d_in[4];
  const float* bkv  = (const float*)d_in[5];
  const float* Wp   = (const float*)d_in[6];
  const float* bp   = (const float*)d_in[7];
  const float* temp = (const float*)d_in[8];

  const size_t SQ = (size_t)BB*CC*HW;
  char* p = (char*)d_ws;
  unsigned short* qn = (unsigned short*)p;  p += SQ*sizeof(unsigned short);
  unsigned short* kn = (unsigned short*)p;  p += SQ*sizeof(unsigned short);
  float* gpart = (float*)p;                 p += (size_t)BB*NHD*32*2304*sizeof(float);
  float* mf = (float*)p;                    p += (size_t)BB*CC*CC*sizeof(float);
  unsigned short* w3b = (unsigned short*)p; p += (size_t)BB*CC*CC*sizeof(unsigned short);
  float* b3 = (float*)p;                    p += (size_t)BB*CC*sizeof(float);
  unsigned short* wb = (unsigned short*)p;  // 2*CC*CC bf16 (Wq | Wk)

  cast_w_kernel<<<dim3((2*CC*CC)/256), 256, 0, stream>>>(Wq, Wkv, wb);

  // fused q+k projection (z: 0=q, 1=k)
  proj_pipe<0><<<dim3(HW/256, BB, 2), 256, 0, stream>>>(
      x_q, x_k, wb, bq, bkv, qn, kn, nullptr);

  gram_kernel<<<dim3(8, NHD, BB), 256, 0, stream>>>(qn, kn, gpart);
  attn_m_kernel<<<dim3(BB*NHD), 256, 0, stream>>>(gpart, Wp, temp, mf);
  w3_kernel<<<dim3(BB, 24), 192, 0, stream>>>(mf, Wkv, bkv, bp, w3b, b3);

  // final: out = W3_b @ x_k + b3_b
  proj_pipe<1><<<dim3(HW/256, BB, 1), 256, 0, stream>>>(
      x_q, x_k, w3b, b3, nullptr, nullptr, nullptr, (float*)d_out);
}

// Round 6
// 214.863 us; speedup vs baseline: 1.4356x; 1.0334x over previous
//
#include <hip/hip_runtime.h>
#include <hip/hip_bf16.h>

#define HW 16384
#define CC 192
#define BB 8
#define NHD 4
#define HD 48

typedef __attribute__((ext_vector_type(8))) short  short8;
typedef __attribute__((ext_vector_type(4))) float  f32x4;

static __device__ __forceinline__ unsigned short f2bf(float f) {
  unsigned u = __float_as_uint(f);
  u += 0x7fffu + ((u >> 16) & 1u);          // round-to-nearest-even
  return (unsigned short)(u >> 16);
}
// two fp32 -> packed bf16x2 (compiler emits v_cvt_pk_bf16_f32)
static __device__ __forceinline__ unsigned pk2bf(float lo, float hi) {
  __hip_bfloat162 h = __float22bfloat162_rn(make_float2(lo, hi));
  return *reinterpret_cast<unsigned*>(&h);
}

// Cast Wq (192x192) and Wk (= Wkv rows 0..191) fp32 -> bf16, contiguous.
__global__ __launch_bounds__(256) void cast_w_kernel(
    const float* __restrict__ Wq, const float* __restrict__ Wkv,
    unsigned short* __restrict__ Wb)
{
  const int i = blockIdx.x * 256 + threadIdx.x;   // 0 .. 2*CC*CC-1
  const float v = (i < CC*CC) ? Wq[i] : Wkv[i - CC*CC];
  Wb[i] = f2bf(v);
}

// Pipelined channel-projection GEMM, double-buffered LDS, ONE barrier/tile.
// 256 threads (wave = head), 256 pos/block in 4 tiles of 64.
// Loop t: issue loads(t+1) -> pre regs; COMPUTE(t) on buf[t&1] (MFMA+epilogue);
// vmcnt-drain; WRITET(t+1) -> buf[t&1^1] (safe: prev barrier proved all waves
// finished reading it); barrier.
// MODE 0: q/k proj (z: 0=q from x_q, 1=k from x_k), +bias, l2norm, bf16 out
// MODE 1: final    (x_k in, per-batch W3b bf16 + b3 fp32 bias, fp32 out)
template<int MODE>
__global__ __launch_bounds__(256) void proj_pipe(
    const float* __restrict__ x_q, const float* __restrict__ x_k,
    const unsigned short* __restrict__ wsrc,
    const float* __restrict__ bias0, const float* __restrict__ bias1,
    unsigned short* __restrict__ oq, unsigned short* __restrict__ ok,
    float* __restrict__ of)
{
  const int tid  = threadIdx.x;
  const int lane = tid & 63;
  const int wv   = tid >> 6;          // wave = head (48 rows)
  const int b    = blockIdx.y;
  const int z    = blockIdx.z;
  const int p0   = blockIdx.x * 256;
  const int l15  = lane & 15;
  const int lg   = lane >> 4;
  const int qd   = tid & 15;          // position-quad owned for staging

  __shared__ unsigned short Xt[2][64][200];  // double-buffered 64x(192+8) bf16

  const float* X = (MODE == 0 ? (z ? x_k : x_q) : x_k) + (size_t)b*CC*HW;
  const unsigned short* Wb = (MODE == 0) ? wsrc + (size_t)z*CC*CC
                                         : wsrc + (size_t)b*CC*CC;
  const float* bias = (MODE == 0) ? (z ? bias1 : bias0) : bias0 + (size_t)b*CC;

  short8 afr[6][3];
  #pragma unroll
  for (int kk = 0; kk < 6; ++kk)
    #pragma unroll
    for (int mt = 0; mt < 3; ++mt)
      afr[kk][mt] = *(const short8*)(Wb + (size_t)(wv*48 + mt*16 + l15)*CC + kk*32 + lg*8);

  float bv[3][4];
  #pragma unroll
  for (int mt = 0; mt < 3; ++mt)
    #pragma unroll
    for (int r = 0; r < 4; ++r)
      bv[mt][r] = bias[wv*48 + mt*16 + lg*4 + r];

  f32x4 pre[12];                      // in-flight tile (12 dwordx4)

  auto LOADT = [&](int pb) {
    #pragma unroll
    for (int i = 0; i < 6; ++i) {
      const int cp = (tid >> 4) + i*16;
      const float* base = X + (size_t)(2*cp)*HW + pb + qd*4;
      pre[2*i]   = *(const f32x4*)(base);
      pre[2*i+1] = *(const f32x4*)(base + HW);
    }
  };
  auto WRITET = [&](int buf) {
    #pragma unroll
    for (int i = 0; i < 6; ++i) {
      const int cp = (tid >> 4) + i*16;
      #pragma unroll
      for (int j = 0; j < 4; ++j)
        *(unsigned*)&Xt[buf][qd*4 + j][2*cp] = pk2bf(pre[2*i][j], pre[2*i+1][j]);
    }
  };

  unsigned short* Obf = nullptr;
  float* Ofp = nullptr;
  if (MODE == 0) Obf = (z ? ok : oq) + (size_t)b*CC*HW;
  else           Ofp = of + (size_t)b*CC*HW;

  auto COMPUTE = [&](int buf, int pb) {
    f32x4 acc[3][4];
    #pragma unroll
    for (int mt = 0; mt < 3; ++mt)
      #pragma unroll
      for (int nt = 0; nt < 4; ++nt)
        acc[mt][nt] = (f32x4){0.f, 0.f, 0.f, 0.f};

    #pragma unroll
    for (int kk = 0; kk < 6; ++kk) {
      short8 bfr[4];
      #pragma unroll
      for (int nt = 0; nt < 4; ++nt)
        bfr[nt] = *(const short8*)&Xt[buf][nt*16 + l15][kk*32 + lg*8];
      #pragma unroll
      for (int mt = 0; mt < 3; ++mt)
        #pragma unroll
        for (int nt = 0; nt < 4; ++nt)
          acc[mt][nt] = __builtin_amdgcn_mfma_f32_16x16x32_bf16(
              afr[kk][mt], bfr[nt], acc[mt][nt], 0, 0, 0);
    }

    #pragma unroll
    for (int nt = 0; nt < 4; ++nt) {
      float v[3][4];
      float ss = 0.f;
      #pragma unroll
      for (int mt = 0; mt < 3; ++mt)
        #pragma unroll
        for (int r = 0; r < 4; ++r) {
          const float x = acc[mt][nt][r] + bv[mt][r];
          v[mt][r] = x;
          ss += x*x;
        }
      if (MODE == 0) {                 // l2norm over the head's 48 rows
        ss += __shfl_xor(ss, 16);
        ss += __shfl_xor(ss, 32);
        const float rn = 1.0f / fmaxf(sqrtf(ss), 1e-12f);
        #pragma unroll
        for (int mt = 0; mt < 3; ++mt)
          #pragma unroll
          for (int r = 0; r < 4; ++r)
            v[mt][r] *= rn;
      }
      const int col = pb + nt*16 + l15;
      if (MODE == 0) {
        #pragma unroll
        for (int mt = 0; mt < 3; ++mt)
          #pragma unroll
          for (int r = 0; r < 4; ++r)
            Obf[(size_t)(wv*48 + mt*16 + lg*4 + r)*HW + col] = f2bf(v[mt][r]);
      } else {
        #pragma unroll
        for (int mt = 0; mt < 3; ++mt)
          #pragma unroll
          for (int r = 0; r < 4; ++r)
            Ofp[(size_t)(wv*48 + mt*16 + lg*4 + r)*HW + col] = v[mt][r];
      }
    }
  };

  // --- pipeline: one barrier per tile ---
  LOADT(p0);
  WRITET(0);
  __syncthreads();
  #pragma unroll
  for (int t = 0; t < 4; ++t) {
    if (t < 3) LOADT(p0 + (t+1)*64);     // loads in flight across compute
    COMPUTE(t & 1, p0 + t*64);
    if (t < 3) {
      WRITET((t & 1) ^ 1);               // other buffer; no pre-barrier needed
      __syncthreads();                   // writes visible for next COMPUTE
    }
  }
}

// Gram: G[b,h,c,k] = sum_p qn[c,p]*kn[k,p]; K-split 32-way, partials to ws.
__global__ __launch_bounds__(256) void gram_kernel(
    const unsigned short* __restrict__ Qn,
    const unsigned short* __restrict__ Kn,
    float* __restrict__ Gpart)
{
  const int tid  = threadIdx.x;
  const int lane = tid & 63;
  const int wv   = tid >> 6;
  const int ks   = blockIdx.x;   // 0..7
  const int h    = blockIdx.y;   // 0..3
  const int b    = blockIdx.z;   // 0..7
  const int l15  = lane & 15;
  const int lg   = lane >> 4;

  const unsigned short* Qb = Qn + ((size_t)b*CC + h*HD)*HW;
  const unsigned short* Kb = Kn + ((size_t)b*CC + h*HD)*HW;
  const int pbase = ks*2048 + wv*512;

  f32x4 acc[3][3];
  #pragma unroll
  for (int mt = 0; mt < 3; ++mt)
    #pragma unroll
    for (int nt = 0; nt < 3; ++nt)
      acc[mt][nt] = (f32x4){0.f, 0.f, 0.f, 0.f};

  for (int it = 0; it < 16; ++it) {
    const int p = pbase + it*32 + lg*8;
    short8 a[3], bb[3];
    #pragma unroll
    for (int mt = 0; mt < 3; ++mt)
      a[mt] = *(const short8*)(Qb + (size_t)(mt*16 + l15)*HW + p);
    #pragma unroll
    for (int nt = 0; nt < 3; ++nt)
      bb[nt] = *(const short8*)(Kb + (size_t)(nt*16 + l15)*HW + p);
    #pragma unroll
    for (int mt = 0; mt < 3; ++mt)
      #pragma unroll
      for (int nt = 0; nt < 3; ++nt)
        acc[mt][nt] = __builtin_amdgcn_mfma_f32_16x16x32_bf16(
            a[mt], bb[nt], acc[mt][nt], 0, 0, 0);
  }

  const int slot = ks*4 + wv;     // 0..31
  float* G = Gpart + ((size_t)(b*NHD + h)*32 + slot)*2304;
  #pragma unroll
  for (int mt = 0; mt < 3; ++mt)
    #pragma unroll
    for (int nt = 0; nt < 3; ++nt)
      #pragma unroll
      for (int r = 0; r < 4; ++r)
        G[(mt*16 + lg*4 + r)*HD + nt*16 + l15] = acc[mt][nt][r];
}

// Per (b,h): reduce Gram partials, wave-parallel row softmax, then
// M[b][o][h*48+k] = sum_c Wp[o][h*48+c] * attn[c][k]  (fp32 out).
__global__ __launch_bounds__(256) void attn_m_kernel(
    const float* __restrict__ Gpart,
    const float* __restrict__ Wp,
    const float* __restrict__ temp,
    float* __restrict__ Mf)
{
  __shared__ float att[HD][52];        // +4 pad
  const int bh  = blockIdx.x;          // 0..31
  const int b   = bh >> 2, h = bh & 3;
  const int tid = threadIdx.x;
  const float* src = Gpart + (size_t)bh*32*2304;

  #pragma unroll
  for (int i = 0; i < 9; ++i) {
    const int e = tid + i*256;         // 2304 = 9*256
    float s = 0.f;
    #pragma unroll
    for (int k = 0; k < 32; ++k) s += src[(size_t)k*2304 + e];
    att[e/48][e%48] = s;
  }
  __syncthreads();

  const int g = tid >> 2, sl = tid & 3;
  if (g < HD) {
    const float t = temp[h];
    const float scale = 0.1f / (1.0f + expf(-t));   // 0.1*sigmoid(t)
    float* row = att[g];
    float m = -1e30f;
    #pragma unroll
    for (int jj = 0; jj < 12; ++jj) m = fmaxf(m, row[sl + jj*4]);
    m = fmaxf(m, __shfl_xor(m, 1));
    m = fmaxf(m, __shfl_xor(m, 2));
    float ev[12];
    float s = 0.f;
    #pragma unroll
    for (int jj = 0; jj < 12; ++jj) {
      const float e = expf((row[sl + jj*4] - m) * scale);
      ev[jj] = e; s += e;
    }
    s += __shfl_xor(s, 1);
    s += __shfl_xor(s, 2);
    const float inv = 1.0f / s;
    #pragma unroll
    for (int jj = 0; jj < 12; ++jj) row[sl + jj*4] = ev[jj] * inv;
  }
  __syncthreads();

  #pragma unroll
  for (int i = 0; i < 36; ++i) {
    const int idx = tid + i*256;       // 0..9215
    const int o = idx / HD, k2 = idx % HD;
    const float* wrow = Wp + (size_t)o*CC + h*HD;
    float s = 0.f;
    #pragma unroll
    for (int c = 0; c < HD; ++c) s += wrow[c] * att[c][k2];
    Mf[(size_t)b*CC*CC + (size_t)o*CC + h*HD + k2] = s;
  }
}

// W3_b = M_b @ Wv (bf16 out), b3_b = M_b @ bv + bp (fp32).
// grid (BB, 24), 192 threads: thread = column j (coalesced Wv reads),
// block = 8 o-rows (M/bv values are lane-uniform -> scalar loads), 8-way ILP.
__global__ __launch_bounds__(192) void w3_kernel(
    const float* __restrict__ Mf, const float* __restrict__ Wkv,
    const float* __restrict__ bkv, const float* __restrict__ bp,
    unsigned short* __restrict__ W3b, float* __restrict__ b3)
{
  const int b  = blockIdx.x;
  const int o0 = blockIdx.y * 8;
  const int j  = threadIdx.x;
  const float* M  = Mf + ((size_t)b*CC + o0)*CC;   // 8 rows x 192, uniform
  const float* Wv = Wkv + (size_t)CC*CC;           // rows 192..383 of Wkv
  const float* bv = bkv + CC;

  float acc[8]  = {0.f,0.f,0.f,0.f,0.f,0.f,0.f,0.f};
  float bacc[8] = {0.f,0.f,0.f,0.f,0.f,0.f,0.f,0.f};
  #pragma unroll 4
  for (int k = 0; k < CC; ++k) {
    const float w  = Wv[(size_t)k*CC + j];   // coalesced across lanes
    const float bk = bv[k];                  // uniform
    #pragma unroll
    for (int r = 0; r < 8; ++r) {
      const float m = M[r*CC + k];           // uniform -> s_load
      acc[r]  += m * w;
      bacc[r] += m * bk;
    }
  }
  unsigned short* dst = W3b + ((size_t)b*CC + o0)*CC + j;
  #pragma unroll
  for (int r = 0; r < 8; ++r) dst[(size_t)r*CC] = f2bf(acc[r]);
  if (j < 8) b3[(size_t)b*CC + o0 + j] = bacc[j] + bp[o0 + j];
}

extern "C" void kernel_launch(void* const* d_in, const int* in_sizes, int n_in,
                              void* d_out, int out_size, void* d_ws, size_t ws_size,
                              hipStream_t stream)
{
  (void)in_sizes; (void)n_in; (void)out_size; (void)ws_size;
  const float* x_q  = (const float*)d_in[0];
  const float* x_k  = (const float*)d_in[1];
  const float* Wq   = (const float*)d_in[2];
  const float* bq   = (const float*)d_in[3];
  const float* Wkv  = (const float*)d_in[4];
  const float* bkv  = (const float*)d_in[5];
  const float* Wp   = (const float*)d_in[6];
  const float* bp   = (const float*)d_in[7];
  const float* temp = (const float*)d_in[8];

  const size_t SQ = (size_t)BB*CC*HW;
  char* p = (char*)d_ws;
  unsigned short* qn = (unsigned short*)p;  p += SQ*sizeof(unsigned short);
  unsigned short* kn = (unsigned short*)p;  p += SQ*sizeof(unsigned short);
  float* gpart = (float*)p;                 p += (size_t)BB*NHD*32*2304*sizeof(float);
  float* mf = (float*)p;                    p += (size_t)BB*CC*CC*sizeof(float);
  unsigned short* w3b = (unsigned short*)p; p += (size_t)BB*CC*CC*sizeof(unsigned short);
  float* b3 = (float*)p;                    p += (size_t)BB*CC*sizeof(float);
  unsigned short* wb = (unsigned short*)p;  // 2*CC*CC bf16 (Wq | Wk)

  cast_w_kernel<<<dim3((2*CC*CC)/256), 256, 0, stream>>>(Wq, Wkv, wb);

  // fused q+k projection (z: 0=q, 1=k)
  proj_pipe<0><<<dim3(HW/256, BB, 2), 256, 0, stream>>>(
      x_q, x_k, wb, bq, bkv, qn, kn, nullptr);

  gram_kernel<<<dim3(8, NHD, BB), 256, 0, stream>>>(qn, kn, gpart);
  attn_m_kernel<<<dim3(BB*NHD), 256, 0, stream>>>(gpart, Wp, temp, mf);
  w3_kernel<<<dim3(BB, 24), 192, 0, stream>>>(mf, Wkv, bkv, bp, w3b, b3);

  // final: out = W3_b @ x_k + b3_b
  proj_pipe<1><<<dim3(HW/256, BB, 1), 256, 0, stream>>>(
      x_q, x_k, w3b, b3, nullptr, nullptr, nullptr, (float*)d_out);
}

// Round 7
// 214.145 us; speedup vs baseline: 1.4405x; 1.0034x over previous
//
#include <hip/hip_runtime.h>
#include <hip/hip_bf16.h>

#define HW 16384
#define CC 192
#define BB 8
#define NHD 4
#define HD 48

typedef __attribute__((ext_vector_type(8))) short  short8;
typedef __attribute__((ext_vector_type(4))) float  f32x4;

static __device__ __forceinline__ unsigned short f2bf(float f) {
  unsigned u = __float_as_uint(f);
  u += 0x7fffu + ((u >> 16) & 1u);          // round-to-nearest-even
  return (unsigned short)(u >> 16);
}
// two fp32 -> packed bf16x2 (compiler emits v_cvt_pk_bf16_f32)
static __device__ __forceinline__ unsigned pk2bf(float lo, float hi) {
  __hip_bfloat162 h = __float22bfloat162_rn(make_float2(lo, hi));
  return *reinterpret_cast<unsigned*>(&h);
}

// Barrier that drains ONLY the LDS/ds counter (lgkmcnt), NOT vmcnt.
// __syncthreads() would emit s_waitcnt vmcnt(0) lgkmcnt(0) before s_barrier,
// forcing every wave to wait for its 48 in-flight global stores each tile.
// LDS visibility across the barrier needs only lgkmcnt(0). Global stores and
// prefetch loads keep draining in the background (T4: never vmcnt(0) in loop).
static __device__ __forceinline__ void ldsbar() {
  asm volatile("" ::: "memory");
  asm volatile("s_waitcnt lgkmcnt(0)" ::: "memory");
  __builtin_amdgcn_s_barrier();
  asm volatile("" ::: "memory");
}

// Cast Wq (192x192) and Wk (= Wkv rows 0..191) fp32 -> bf16, contiguous.
__global__ __launch_bounds__(256) void cast_w_kernel(
    const float* __restrict__ Wq, const float* __restrict__ Wkv,
    unsigned short* __restrict__ Wb)
{
  const int i = blockIdx.x * 256 + threadIdx.x;   // 0 .. 2*CC*CC-1
  const float v = (i < CC*CC) ? Wq[i] : Wkv[i - CC*CC];
  Wb[i] = f2bf(v);
}

// Pipelined channel-projection GEMM, double-buffered LDS, one lgkm-only
// barrier per tile. 256 threads (wave = head), 256 pos/block in 4 tiles of 64.
// MODE 0: q/k proj (z: 0=q from x_q, 1=k from x_k), +bias, l2norm, bf16 out
// MODE 1: final    (x_k in, per-batch W3b bf16 + b3 fp32 bias, fp32 out)
template<int MODE>
__global__ __launch_bounds__(256) void proj_pipe(
    const float* __restrict__ x_q, const float* __restrict__ x_k,
    const unsigned short* __restrict__ wsrc,
    const float* __restrict__ bias0, const float* __restrict__ bias1,
    unsigned short* __restrict__ oq, unsigned short* __restrict__ ok,
    float* __restrict__ of)
{
  const int tid  = threadIdx.x;
  const int lane = tid & 63;
  const int wv   = tid >> 6;          // wave = head (48 rows)
  const int b    = blockIdx.y;
  const int z    = blockIdx.z;
  const int p0   = blockIdx.x * 256;
  const int l15  = lane & 15;
  const int lg   = lane >> 4;
  const int qd   = tid & 15;          // position-quad owned for staging

  __shared__ unsigned short Xt[2][64][200];  // double-buffered 64x(192+8) bf16

  const float* X = (MODE == 0 ? (z ? x_k : x_q) : x_k) + (size_t)b*CC*HW;
  const unsigned short* Wb = (MODE == 0) ? wsrc + (size_t)z*CC*CC
                                         : wsrc + (size_t)b*CC*CC;
  const float* bias = (MODE == 0) ? (z ? bias1 : bias0) : bias0 + (size_t)b*CC;

  short8 afr[6][3];
  #pragma unroll
  for (int kk = 0; kk < 6; ++kk)
    #pragma unroll
    for (int mt = 0; mt < 3; ++mt)
      afr[kk][mt] = *(const short8*)(Wb + (size_t)(wv*48 + mt*16 + l15)*CC + kk*32 + lg*8);

  float bv[3][4];
  #pragma unroll
  for (int mt = 0; mt < 3; ++mt)
    #pragma unroll
    for (int r = 0; r < 4; ++r)
      bv[mt][r] = bias[wv*48 + mt*16 + lg*4 + r];

  f32x4 pre[12];                      // in-flight tile (12 dwordx4)

  auto LOADT = [&](int pb) {
    #pragma unroll
    for (int i = 0; i < 6; ++i) {
      const int cp = (tid >> 4) + i*16;
      const float* base = X + (size_t)(2*cp)*HW + pb + qd*4;
      pre[2*i]   = *(const f32x4*)(base);
      pre[2*i+1] = *(const f32x4*)(base + HW);
    }
  };
  auto WRITET = [&](int buf) {
    #pragma unroll
    for (int i = 0; i < 6; ++i) {
      const int cp = (tid >> 4) + i*16;
      #pragma unroll
      for (int j = 0; j < 4; ++j)
        *(unsigned*)&Xt[buf][qd*4 + j][2*cp] = pk2bf(pre[2*i][j], pre[2*i+1][j]);
    }
  };

  unsigned short* Obf = nullptr;
  float* Ofp = nullptr;
  if (MODE == 0) Obf = (z ? ok : oq) + (size_t)b*CC*HW;
  else           Ofp = of + (size_t)b*CC*HW;

  auto COMPUTE = [&](int buf, int pb) {
    f32x4 acc[3][4];
    #pragma unroll
    for (int mt = 0; mt < 3; ++mt)
      #pragma unroll
      for (int nt = 0; nt < 4; ++nt)
        acc[mt][nt] = (f32x4){0.f, 0.f, 0.f, 0.f};

    #pragma unroll
    for (int kk = 0; kk < 6; ++kk) {
      short8 bfr[4];
      #pragma unroll
      for (int nt = 0; nt < 4; ++nt)
        bfr[nt] = *(const short8*)&Xt[buf][nt*16 + l15][kk*32 + lg*8];
      #pragma unroll
      for (int mt = 0; mt < 3; ++mt)
        #pragma unroll
        for (int nt = 0; nt < 4; ++nt)
          acc[mt][nt] = __builtin_amdgcn_mfma_f32_16x16x32_bf16(
              afr[kk][mt], bfr[nt], acc[mt][nt], 0, 0, 0);
    }

    #pragma unroll
    for (int nt = 0; nt < 4; ++nt) {
      float v[3][4];
      float ss = 0.f;
      #pragma unroll
      for (int mt = 0; mt < 3; ++mt)
        #pragma unroll
        for (int r = 0; r < 4; ++r) {
          const float x = acc[mt][nt][r] + bv[mt][r];
          v[mt][r] = x;
          ss += x*x;
        }
      if (MODE == 0) {                 // l2norm over the head's 48 rows
        ss += __shfl_xor(ss, 16);
        ss += __shfl_xor(ss, 32);
        const float rn = 1.0f / fmaxf(sqrtf(ss), 1e-12f);
        #pragma unroll
        for (int mt = 0; mt < 3; ++mt)
          #pragma unroll
          for (int r = 0; r < 4; ++r)
            v[mt][r] *= rn;
      }
      const int col = pb + nt*16 + l15;
      if (MODE == 0) {
        #pragma unroll
        for (int mt = 0; mt < 3; ++mt)
          #pragma unroll
          for (int r = 0; r < 4; ++r)
            Obf[(size_t)(wv*48 + mt*16 + lg*4 + r)*HW + col] = f2bf(v[mt][r]);
      } else {
        #pragma unroll
        for (int mt = 0; mt < 3; ++mt)
          #pragma unroll
          for (int r = 0; r < 4; ++r)
            Ofp[(size_t)(wv*48 + mt*16 + lg*4 + r)*HW + col] = v[mt][r];
      }
    }
  };

  // --- pipeline: one lgkm-only barrier per tile; stores drain in background ---
  LOADT(p0);
  WRITET(0);
  ldsbar();
  #pragma unroll
  for (int t = 0; t < 4; ++t) {
    if (t < 3) LOADT(p0 + (t+1)*64);     // loads in flight across compute
    COMPUTE(t & 1, p0 + t*64);
    if (t < 3) {
      WRITET((t & 1) ^ 1);               // other buffer; prev barrier freed it
      ldsbar();                          // ds_writes visible; vmcnt NOT drained
    }
  }
}

// Gram: G[b,h,c,k] = sum_p qn[c,p]*kn[k,p]; K-split 32-way, partials to ws.
__global__ __launch_bounds__(256) void gram_kernel(
    const unsigned short* __restrict__ Qn,
    const unsigned short* __restrict__ Kn,
    float* __restrict__ Gpart)
{
  const int tid  = threadIdx.x;
  const int lane = tid & 63;
  const int wv   = tid >> 6;
  const int ks   = blockIdx.x;   // 0..7
  const int h    = blockIdx.y;   // 0..3
  const int b    = blockIdx.z;   // 0..7
  const int l15  = lane & 15;
  const int lg   = lane >> 4;

  const unsigned short* Qb = Qn + ((size_t)b*CC + h*HD)*HW;
  const unsigned short* Kb = Kn + ((size_t)b*CC + h*HD)*HW;
  const int pbase = ks*2048 + wv*512;

  f32x4 acc[3][3];
  #pragma unroll
  for (int mt = 0; mt < 3; ++mt)
    #pragma unroll
    for (int nt = 0; nt < 3; ++nt)
      acc[mt][nt] = (f32x4){0.f, 0.f, 0.f, 0.f};

  for (int it = 0; it < 16; ++it) {
    const int p = pbase + it*32 + lg*8;
    short8 a[3], bb[3];
    #pragma unroll
    for (int mt = 0; mt < 3; ++mt)
      a[mt] = *(const short8*)(Qb + (size_t)(mt*16 + l15)*HW + p);
    #pragma unroll
    for (int nt = 0; nt < 3; ++nt)
      bb[nt] = *(const short8*)(Kb + (size_t)(nt*16 + l15)*HW + p);
    #pragma unroll
    for (int mt = 0; mt < 3; ++mt)
      #pragma unroll
      for (int nt = 0; nt < 3; ++nt)
        acc[mt][nt] = __builtin_amdgcn_mfma_f32_16x16x32_bf16(
            a[mt], bb[nt], acc[mt][nt], 0, 0, 0);
  }

  const int slot = ks*4 + wv;     // 0..31
  float* G = Gpart + ((size_t)(b*NHD + h)*32 + slot)*2304;
  #pragma unroll
  for (int mt = 0; mt < 3; ++mt)
    #pragma unroll
    for (int nt = 0; nt < 3; ++nt)
      #pragma unroll
      for (int r = 0; r < 4; ++r)
        G[(mt*16 + lg*4 + r)*HD + nt*16 + l15] = acc[mt][nt][r];
}

// Per (b,h): reduce Gram partials, wave-parallel row softmax, then
// M[b][o][h*48+k] = sum_c Wp[o][h*48+c] * attn[c][k]  (fp32 out).
__global__ __launch_bounds__(256) void attn_m_kernel(
    const float* __restrict__ Gpart,
    const float* __restrict__ Wp,
    const float* __restrict__ temp,
    float* __restrict__ Mf)
{
  __shared__ float att[HD][52];        // +4 pad
  const int bh  = blockIdx.x;          // 0..31
  const int b   = bh >> 2, h = bh & 3;
  const int tid = threadIdx.x;
  const float* src = Gpart + (size_t)bh*32*2304;

  #pragma unroll
  for (int i = 0; i < 9; ++i) {
    const int e = tid + i*256;         // 2304 = 9*256
    float s = 0.f;
    #pragma unroll
    for (int k = 0; k < 32; ++k) s += src[(size_t)k*2304 + e];
    att[e/48][e%48] = s;
  }
  __syncthreads();

  const int g = tid >> 2, sl = tid & 3;
  if (g < HD) {
    const float t = temp[h];
    const float scale = 0.1f / (1.0f + expf(-t));   // 0.1*sigmoid(t)
    float* row = att[g];
    float m = -1e30f;
    #pragma unroll
    for (int jj = 0; jj < 12; ++jj) m = fmaxf(m, row[sl + jj*4]);
    m = fmaxf(m, __shfl_xor(m, 1));
    m = fmaxf(m, __shfl_xor(m, 2));
    float ev[12];
    float s = 0.f;
    #pragma unroll
    for (int jj = 0; jj < 12; ++jj) {
      const float e = expf((row[sl + jj*4] - m) * scale);
      ev[jj] = e; s += e;
    }
    s += __shfl_xor(s, 1);
    s += __shfl_xor(s, 2);
    const float inv = 1.0f / s;
    #pragma unroll
    for (int jj = 0; jj < 12; ++jj) row[sl + jj*4] = ev[jj] * inv;
  }
  __syncthreads();

  #pragma unroll
  for (int i = 0; i < 36; ++i) {
    const int idx = tid + i*256;       // 0..9215
    const int o = idx / HD, k2 = idx % HD;
    const float* wrow = Wp + (size_t)o*CC + h*HD;
    float s = 0.f;
    #pragma unroll
    for (int c = 0; c < HD; ++c) s += wrow[c] * att[c][k2];
    Mf[(size_t)b*CC*CC + (size_t)o*CC + h*HD + k2] = s;
  }
}

// W3_b = M_b @ Wv (bf16 out), b3_b = M_b @ bv + bp (fp32).
// grid (BB, 24), 192 threads: thread = column j (coalesced Wv reads),
// block = 8 o-rows (M/bv values are lane-uniform -> scalar loads), 8-way ILP.
__global__ __launch_bounds__(192) void w3_kernel(
    const float* __restrict__ Mf, const float* __restrict__ Wkv,
    const float* __restrict__ bkv, const float* __restrict__ bp,
    unsigned short* __restrict__ W3b, float* __restrict__ b3)
{
  const int b  = blockIdx.x;
  const int o0 = blockIdx.y * 8;
  const int j  = threadIdx.x;
  const float* M  = Mf + ((size_t)b*CC + o0)*CC;   // 8 rows x 192, uniform
  const float* Wv = Wkv + (size_t)CC*CC;           // rows 192..383 of Wkv
  const float* bv = bkv + CC;

  float acc[8]  = {0.f,0.f,0.f,0.f,0.f,0.f,0.f,0.f};
  float bacc[8] = {0.f,0.f,0.f,0.f,0.f,0.f,0.f,0.f};
  #pragma unroll 4
  for (int k = 0; k < CC; ++k) {
    const float w  = Wv[(size_t)k*CC + j];   // coalesced across lanes
    const float bk = bv[k];                  // uniform
    #pragma unroll
    for (int r = 0; r < 8; ++r) {
      const float m = M[r*CC + k];           // uniform -> s_load
      acc[r]  += m * w;
      bacc[r] += m * bk;
    }
  }
  unsigned short* dst = W3b + ((size_t)b*CC + o0)*CC + j;
  #pragma unroll
  for (int r = 0; r < 8; ++r) dst[(size_t)r*CC] = f2bf(acc[r]);
  if (j < 8) b3[(size_t)b*CC + o0 + j] = bacc[j] + bp[o0 + j];
}

extern "C" void kernel_launch(void* const* d_in, const int* in_sizes, int n_in,
                              void* d_out, int out_size, void* d_ws, size_t ws_size,
                              hipStream_t stream)
{
  (void)in_sizes; (void)n_in; (void)out_size; (void)ws_size;
  const float* x_q  = (const float*)d_in[0];
  const float* x_k  = (const float*)d_in[1];
  const float* Wq   = (const float*)d_in[2];
  const float* bq   = (const float*)d_in[3];
  const float* Wkv  = (const float*)d_in[4];
  const float* bkv  = (const float*)d_in[5];
  const float* Wp   = (const float*)d_in[6];
  const float* bp   = (const float*)d_in[7];
  const float* temp = (const float*)d_in[8];

  const size_t SQ = (size_t)BB*CC*HW;
  char* p = (char*)d_ws;
  unsigned short* qn = (unsigned short*)p;  p += SQ*sizeof(unsigned short);
  unsigned short* kn = (unsigned short*)p;  p += SQ*sizeof(unsigned short);
  float* gpart = (float*)p;                 p += (size_t)BB*NHD*32*2304*sizeof(float);
  float* mf = (float*)p;                    p += (size_t)BB*CC*CC*sizeof(float);
  unsigned short* w3b = (unsigned short*)p; p += (size_t)BB*CC*CC*sizeof(unsigned short);
  float* b3 = (float*)p;                    p += (size_t)BB*CC*sizeof(float);
  unsigned short* wb = (unsigned short*)p;  // 2*CC*CC bf16 (Wq | Wk)

  cast_w_kernel<<<dim3((2*CC*CC)/256), 256, 0, stream>>>(Wq, Wkv, wb);

  // fused q+k projection (z: 0=q, 1=k)
  proj_pipe<0><<<dim3(HW/256, BB, 2), 256, 0, stream>>>(
      x_q, x_k, wb, bq, bkv, qn, kn, nullptr);

  gram_kernel<<<dim3(8, NHD, BB), 256, 0, stream>>>(qn, kn, gpart);
  attn_m_kernel<<<dim3(BB*NHD), 256, 0, stream>>>(gpart, Wp, temp, mf);
  w3_kernel<<<dim3(BB, 24), 192, 0, stream>>>(mf, Wkv, bkv, bp, w3b, b3);

  // final: out = W3_b @ x_k + b3_b
  proj_pipe<1><<<dim3(HW/256, BB, 1), 256, 0, stream>>>(
      x_q, x_k, w3b, b3, nullptr, nullptr, nullptr, (float*)d_out);
}

// Round 8
// 170.371 us; speedup vs baseline: 1.8106x; 1.2569x over previous
//
#include <hip/hip_runtime.h>
#include <hip/hip_bf16.h>

#define HW 16384
#define CC 192
#define BB 8
#define NHD 4
#define HD 48

typedef __attribute__((ext_vector_type(8))) short  short8;
typedef __attribute__((ext_vector_type(4))) float  f32x4;

static __device__ __forceinline__ unsigned short f2bf(float f) {
  unsigned u = __float_as_uint(f);
  u += 0x7fffu + ((u >> 16) & 1u);          // round-to-nearest-even
  return (unsigned short)(u >> 16);
}
// two fp32 -> packed bf16x2 (compiler emits v_cvt_pk_bf16_f32)
static __device__ __forceinline__ unsigned pk2bf(float lo, float hi) {
  __hip_bfloat162 h = __float22bfloat162_rn(make_float2(lo, hi));
  return *reinterpret_cast<unsigned*>(&h);
}

// lgkm-only barrier: LDS visibility without draining vmcnt (T4).
static __device__ __forceinline__ void ldsbar() {
  asm volatile("" ::: "memory");
  asm volatile("s_waitcnt lgkmcnt(0)" ::: "memory");
  __builtin_amdgcn_s_barrier();
  asm volatile("" ::: "memory");
}

// Cast Wq (192x192) and Wk (= Wkv rows 0..191) fp32 -> bf16, contiguous.
__global__ __launch_bounds__(256) void cast_w_kernel(
    const float* __restrict__ Wq, const float* __restrict__ Wkv,
    unsigned short* __restrict__ Wb)
{
  const int i = blockIdx.x * 256 + threadIdx.x;   // 0 .. 2*CC*CC-1
  const float v = (i < CC*CC) ? Wq[i] : Wkv[i - CC*CC];
  Wb[i] = f2bf(v);
}

// ---------------------------------------------------------------------------
// Fused q-proj + k-proj + gram. Per block: 256 positions (4 tiles of 64),
// wave = head. qn/kn live only in LDS; gram partials (48x48 per head) are
// accumulated in registers across tiles and written once per block.
// LDS: Xs 25.6KB (re-staged q then k per tile) + QN/KN 4x48x68 bf16 (52.2KB)
//      = 77.8KB -> 2 blocks/CU. VGPR capped by __launch_bounds__(256,2).
// ---------------------------------------------------------------------------
__global__ __launch_bounds__(256, 2) void qkg_kernel(
    const float* __restrict__ x_q, const float* __restrict__ x_k,
    const unsigned short* __restrict__ wb,   // [2][CC][CC] bf16 (Wq | Wk)
    const float* __restrict__ bq, const float* __restrict__ bkv,
    float* __restrict__ gpart)
{
  const int tid  = threadIdx.x;
  const int lane = tid & 63;
  const int wv   = tid >> 6;          // wave = head
  const int b    = blockIdx.y;
  const int p0   = blockIdx.x * 256;
  const int l15  = lane & 15;
  const int lg   = lane >> 4;
  const int qd   = tid & 15;

  __shared__ unsigned short Xs[64][200];      // 25.6 KB, shared q/k staging
  __shared__ unsigned short QN[NHD][48][68];  // 26.1 KB (pad 68: stride 34 dw)
  __shared__ unsigned short KN[NHD][48][68];  // 26.1 KB

  const float* Xq = x_q + (size_t)b*CC*HW;
  const float* Xk = x_k + (size_t)b*CC*HW;

  f32x4 pre[12];
  auto LOADT = [&](const float* X, int pb) {
    #pragma unroll
    for (int i = 0; i < 6; ++i) {
      const int cp = (tid >> 4) + i*16;
      const float* base = X + (size_t)(2*cp)*HW + pb + qd*4;
      pre[2*i]   = *(const f32x4*)(base);
      pre[2*i+1] = *(const f32x4*)(base + HW);
    }
  };
  auto WRITET = [&]() {
    #pragma unroll
    for (int i = 0; i < 6; ++i) {
      const int cp = (tid >> 4) + i*16;
      #pragma unroll
      for (int j = 0; j < 4; ++j)
        *(unsigned*)&Xs[qd*4 + j][2*cp] = pk2bf(pre[2*i][j], pre[2*i+1][j]);
    }
  };

  // Projection + bias + l2norm; result -> DST[c_local][p_local] (bf16).
  // Weight frags loaded per-kk from L2 (shared by all blocks -> broadcast).
  auto PROJ = [&](const unsigned short* W, const float* bias,
                  unsigned short (*DST)[68]) {
    f32x4 acc[3][4];
    #pragma unroll
    for (int mt = 0; mt < 3; ++mt)
      #pragma unroll
      for (int nt = 0; nt < 4; ++nt)
        acc[mt][nt] = (f32x4){0.f, 0.f, 0.f, 0.f};

    #pragma unroll
    for (int kk = 0; kk < 6; ++kk) {
      short8 afr[3], bfr[4];
      #pragma unroll
      for (int mt = 0; mt < 3; ++mt)
        afr[mt] = *(const short8*)(W + (size_t)(wv*48 + mt*16 + l15)*CC + kk*32 + lg*8);
      #pragma unroll
      for (int nt = 0; nt < 4; ++nt)
        bfr[nt] = *(const short8*)&Xs[nt*16 + l15][kk*32 + lg*8];
      #pragma unroll
      for (int mt = 0; mt < 3; ++mt)
        #pragma unroll
        for (int nt = 0; nt < 4; ++nt)
          acc[mt][nt] = __builtin_amdgcn_mfma_f32_16x16x32_bf16(
              afr[mt], bfr[nt], acc[mt][nt], 0, 0, 0);
    }

    #pragma unroll
    for (int nt = 0; nt < 4; ++nt) {
      float v[3][4];
      float ss = 0.f;
      #pragma unroll
      for (int mt = 0; mt < 3; ++mt)
        #pragma unroll
        for (int r = 0; r < 4; ++r) {
          const float x = acc[mt][nt][r] + bias[wv*48 + mt*16 + lg*4 + r];
          v[mt][r] = x;
          ss += x*x;
        }
      ss += __shfl_xor(ss, 16);
      ss += __shfl_xor(ss, 32);
      const float rn = 1.0f / fmaxf(sqrtf(ss), 1e-12f);
      #pragma unroll
      for (int mt = 0; mt < 3; ++mt)
        #pragma unroll
        for (int r = 0; r < 4; ++r)
          DST[mt*16 + lg*4 + r][nt*16 + l15] = f2bf(v[mt][r] * rn);
    }
  };

  f32x4 gacc[3][3];
  #pragma unroll
  for (int mt = 0; mt < 3; ++mt)
    #pragma unroll
    for (int nt = 0; nt < 3; ++nt)
      gacc[mt][nt] = (f32x4){0.f, 0.f, 0.f, 0.f};

  LOADT(Xq, p0);
  for (int t = 0; t < 4; ++t) {
    const int pb = p0 + t*64;
    WRITET();                          // q tile -> Xs
    ldsbar();
    LOADT(Xk, pb);                     // k loads in flight during q compute
    PROJ(wb, bq, QN[wv]);              // q: MFMA + norm -> QN
    ldsbar();                          // all waves done reading Xs(q)
    WRITET();                          // k tile -> Xs
    ldsbar();
    if (t < 3) LOADT(Xq, pb + 64);     // next q in flight during k compute
    PROJ(wb + (size_t)CC*CC, bkv, KN[wv]);  // k: MFMA + norm -> KN
    ldsbar();                          // (uniform barrier count across waves)

    // gram: wave-private (own head's QN/KN only) -> no barrier needed
    #pragma unroll
    for (int s = 0; s < 2; ++s) {
      short8 ga[3], gb[3];
      #pragma unroll
      for (int mt = 0; mt < 3; ++mt)
        ga[mt] = *(const short8*)&QN[wv][mt*16 + l15][s*32 + lg*8];
      #pragma unroll
      for (int nt = 0; nt < 3; ++nt)
        gb[nt] = *(const short8*)&KN[wv][nt*16 + l15][s*32 + lg*8];
      #pragma unroll
      for (int mt = 0; mt < 3; ++mt)
        #pragma unroll
        for (int nt = 0; nt < 3; ++nt)
          gacc[mt][nt] = __builtin_amdgcn_mfma_f32_16x16x32_bf16(
              ga[mt], gb[nt], gacc[mt][nt], 0, 0, 0);
    }
  }

  // write 48x48 gram partial for (b, head=wv), slot = blockIdx.x (0..63)
  float* G = gpart + ((size_t)(b*NHD + wv)*64 + blockIdx.x)*2304;
  #pragma unroll
  for (int mt = 0; mt < 3; ++mt)
    #pragma unroll
    for (int nt = 0; nt < 3; ++nt)
      #pragma unroll
      for (int r = 0; r < 4; ++r)
        G[(mt*16 + lg*4 + r)*HD + nt*16 + l15] = gacc[mt][nt][r];
}

// Final projection: out = W3_b @ x_k + b3_b (pipelined, dbuf, lgkm barriers).
__global__ __launch_bounds__(256) void proj_fin(
    const float* __restrict__ x_k,
    const unsigned short* __restrict__ w3b,
    const float* __restrict__ b3,
    float* __restrict__ of)
{
  const int tid  = threadIdx.x;
  const int lane = tid & 63;
  const int wv   = tid >> 6;
  const int b    = blockIdx.y;
  const int p0   = blockIdx.x * 256;
  const int l15  = lane & 15;
  const int lg   = lane >> 4;
  const int qd   = tid & 15;

  __shared__ unsigned short Xt[2][64][200];

  const float* X = x_k + (size_t)b*CC*HW;
  const unsigned short* Wb = w3b + (size_t)b*CC*CC;
  const float* bias = b3 + (size_t)b*CC;

  short8 afr[6][3];
  #pragma unroll
  for (int kk = 0; kk < 6; ++kk)
    #pragma unroll
    for (int mt = 0; mt < 3; ++mt)
      afr[kk][mt] = *(const short8*)(Wb + (size_t)(wv*48 + mt*16 + l15)*CC + kk*32 + lg*8);

  float bv[3][4];
  #pragma unroll
  for (int mt = 0; mt < 3; ++mt)
    #pragma unroll
    for (int r = 0; r < 4; ++r)
      bv[mt][r] = bias[wv*48 + mt*16 + lg*4 + r];

  f32x4 pre[12];
  auto LOADT = [&](int pb) {
    #pragma unroll
    for (int i = 0; i < 6; ++i) {
      const int cp = (tid >> 4) + i*16;
      const float* base = X + (size_t)(2*cp)*HW + pb + qd*4;
      pre[2*i]   = *(const f32x4*)(base);
      pre[2*i+1] = *(const f32x4*)(base + HW);
    }
  };
  auto WRITET = [&](int buf) {
    #pragma unroll
    for (int i = 0; i < 6; ++i) {
      const int cp = (tid >> 4) + i*16;
      #pragma unroll
      for (int j = 0; j < 4; ++j)
        *(unsigned*)&Xt[buf][qd*4 + j][2*cp] = pk2bf(pre[2*i][j], pre[2*i+1][j]);
    }
  };

  float* Ofp = of + (size_t)b*CC*HW;

  auto COMPUTE = [&](int buf, int pb) {
    f32x4 acc[3][4];
    #pragma unroll
    for (int mt = 0; mt < 3; ++mt)
      #pragma unroll
      for (int nt = 0; nt < 4; ++nt)
        acc[mt][nt] = (f32x4){0.f, 0.f, 0.f, 0.f};

    #pragma unroll
    for (int kk = 0; kk < 6; ++kk) {
      short8 bfr[4];
      #pragma unroll
      for (int nt = 0; nt < 4; ++nt)
        bfr[nt] = *(const short8*)&Xt[buf][nt*16 + l15][kk*32 + lg*8];
      #pragma unroll
      for (int mt = 0; mt < 3; ++mt)
        #pragma unroll
        for (int nt = 0; nt < 4; ++nt)
          acc[mt][nt] = __builtin_amdgcn_mfma_f32_16x16x32_bf16(
              afr[kk][mt], bfr[nt], acc[mt][nt], 0, 0, 0);
    }

    #pragma unroll
    for (int nt = 0; nt < 4; ++nt) {
      const int col = pb + nt*16 + l15;
      #pragma unroll
      for (int mt = 0; mt < 3; ++mt)
        #pragma unroll
        for (int r = 0; r < 4; ++r)
          Ofp[(size_t)(wv*48 + mt*16 + lg*4 + r)*HW + col] = acc[mt][nt][r] + bv[mt][r];
    }
  };

  LOADT(p0);
  WRITET(0);
  ldsbar();
  #pragma unroll
  for (int t = 0; t < 4; ++t) {
    if (t < 3) LOADT(p0 + (t+1)*64);
    COMPUTE(t & 1, p0 + t*64);
    if (t < 3) {
      WRITET((t & 1) ^ 1);
      ldsbar();
    }
  }
}

// Per (b,h): reduce 64 gram partials, wave-parallel row softmax, then
// M[b][o][h*48+k] = sum_c Wp[o][h*48+c] * attn[c][k]  (fp32 out).
__global__ __launch_bounds__(256) void attn_m_kernel(
    const float* __restrict__ Gpart,
    const float* __restrict__ Wp,
    const float* __restrict__ temp,
    float* __restrict__ Mf)
{
  __shared__ float att[HD][52];
  const int bh  = blockIdx.x;          // 0..31
  const int b   = bh >> 2, h = bh & 3;
  const int tid = threadIdx.x;
  const float* src = Gpart + (size_t)bh*64*2304;

  #pragma unroll
  for (int i = 0; i < 9; ++i) {
    const int e = tid + i*256;         // 2304 = 9*256
    float s = 0.f;
    #pragma unroll
    for (int k = 0; k < 64; ++k) s += src[(size_t)k*2304 + e];
    att[e/48][e%48] = s;
  }
  __syncthreads();

  const int g = tid >> 2, sl = tid & 3;
  if (g < HD) {
    const float t = temp[h];
    const float scale = 0.1f / (1.0f + expf(-t));   // 0.1*sigmoid(t)
    float* row = att[g];
    float m = -1e30f;
    #pragma unroll
    for (int jj = 0; jj < 12; ++jj) m = fmaxf(m, row[sl + jj*4]);
    m = fmaxf(m, __shfl_xor(m, 1));
    m = fmaxf(m, __shfl_xor(m, 2));
    float ev[12];
    float s = 0.f;
    #pragma unroll
    for (int jj = 0; jj < 12; ++jj) {
      const float e = expf((row[sl + jj*4] - m) * scale);
      ev[jj] = e; s += e;
    }
    s += __shfl_xor(s, 1);
    s += __shfl_xor(s, 2);
    const float inv = 1.0f / s;
    #pragma unroll
    for (int jj = 0; jj < 12; ++jj) row[sl + jj*4] = ev[jj] * inv;
  }
  __syncthreads();

  #pragma unroll
  for (int i = 0; i < 36; ++i) {
    const int idx = tid + i*256;
    const int o = idx / HD, k2 = idx % HD;
    const float* wrow = Wp + (size_t)o*CC + h*HD;
    float s = 0.f;
    #pragma unroll
    for (int c = 0; c < HD; ++c) s += wrow[c] * att[c][k2];
    Mf[(size_t)b*CC*CC + (size_t)o*CC + h*HD + k2] = s;
  }
}

// W3_b = M_b @ Wv (bf16 out), b3_b = M_b @ bv + bp (fp32).
__global__ __launch_bounds__(192) void w3_kernel(
    const float* __restrict__ Mf, const float* __restrict__ Wkv,
    const float* __restrict__ bkv, const float* __restrict__ bp,
    unsigned short* __restrict__ W3b, float* __restrict__ b3)
{
  const int b  = blockIdx.x;
  const int o0 = blockIdx.y * 8;
  const int j  = threadIdx.x;
  const float* M  = Mf + ((size_t)b*CC + o0)*CC;
  const float* Wv = Wkv + (size_t)CC*CC;
  const float* bv = bkv + CC;

  float acc[8]  = {0.f,0.f,0.f,0.f,0.f,0.f,0.f,0.f};
  float bacc[8] = {0.f,0.f,0.f,0.f,0.f,0.f,0.f,0.f};
  #pragma unroll 4
  for (int k = 0; k < CC; ++k) {
    const float w  = Wv[(size_t)k*CC + j];
    const float bk = bv[k];
    #pragma unroll
    for (int r = 0; r < 8; ++r) {
      const float m = M[r*CC + k];
      acc[r]  += m * w;
      bacc[r] += m * bk;
    }
  }
  unsigned short* dst = W3b + ((size_t)b*CC + o0)*CC + j;
  #pragma unroll
  for (int r = 0; r < 8; ++r) dst[(size_t)r*CC] = f2bf(acc[r]);
  if (j < 8) b3[(size_t)b*CC + o0 + j] = bacc[j] + bp[o0 + j];
}

extern "C" void kernel_launch(void* const* d_in, const int* in_sizes, int n_in,
                              void* d_out, int out_size, void* d_ws, size_t ws_size,
                              hipStream_t stream)
{
  (void)in_sizes; (void)n_in; (void)out_size; (void)ws_size;
  const float* x_q  = (const float*)d_in[0];
  const float* x_k  = (const float*)d_in[1];
  const float* Wq   = (const float*)d_in[2];
  const float* bq   = (const float*)d_in[3];
  const float* Wkv  = (const float*)d_in[4];
  const float* bkv  = (const float*)d_in[5];
  const float* Wp   = (const float*)d_in[6];
  const float* bp   = (const float*)d_in[7];
  const float* temp = (const float*)d_in[8];

  char* p = (char*)d_ws;
  float* gpart = (float*)p;                 p += (size_t)BB*NHD*64*2304*sizeof(float);
  float* mf = (float*)p;                    p += (size_t)BB*CC*CC*sizeof(float);
  unsigned short* w3b = (unsigned short*)p; p += (size_t)BB*CC*CC*sizeof(unsigned short);
  float* b3 = (float*)p;                    p += (size_t)BB*CC*sizeof(float);
  unsigned short* wb = (unsigned short*)p;  // 2*CC*CC bf16 (Wq | Wk)

  cast_w_kernel<<<dim3((2*CC*CC)/256), 256, 0, stream>>>(Wq, Wkv, wb);

  // fused q-proj + k-proj + gram (qn/kn stay in LDS)
  qkg_kernel<<<dim3(HW/256, BB), 256, 0, stream>>>(
      x_q, x_k, wb, bq, bkv, gpart);

  attn_m_kernel<<<dim3(BB*NHD), 256, 0, stream>>>(gpart, Wp, temp, mf);
  w3_kernel<<<dim3(BB, 24), 192, 0, stream>>>(mf, Wkv, bkv, bp, w3b, b3);

  // final: out = W3_b @ x_k + b3_b
  proj_fin<<<dim3(HW/256, BB), 256, 0, stream>>>(x_k, w3b, b3, (float*)d_out);
}